// Round 11
// baseline (82.717 us; speedup 1.0000x reference)
//
#include <hip/hip_runtime.h>

#define CQ 32
#define KQ 128
#define OUTN 1024
#define BQ 8
#define NACC (BQ * OUTN)
#define HSZ 1024
#define PPW 3                         // points per lane per wave (384 / 64 / 2)
#define WPG 2                         // waves per group
#define NTHR (WPG * 64)               // 128
#define NGROUP (BQ * KQ)              // 1024 groups = 1024 blocks
#define WS_NEED ((size_t)NGROUP * OUTN * sizeof(float))
#define K2 0.84934044f                // sqrt(0.5*log2(e)): exp(-0.5 x) = exp2(-(sqrt(.5 log2e) d)^2 ...)

__global__ void zero_out(float* __restrict__ out) {
    int i = blockIdx.x * blockDim.x + threadIdx.x;
    if (i < NACC) out[i] = 0.0f;
}

// wave64 sum via DPP; result valid in lane 63 (invalid-source lanes read 0).
__device__ __forceinline__ float wave_red_dpp(float v) {
#define DPPADD(ctrl)                                                              \
    {                                                                             \
        int t_ = __builtin_amdgcn_update_dpp(0, __float_as_int(v), (ctrl), 0xF,   \
                                             0xF, true);                          \
        v += __int_as_float(t_);                                                  \
    }
    DPPADD(0x111)  // row_shr:1
    DPPADD(0x112)  // row_shr:2
    DPPADD(0x114)  // row_shr:4
    DPPADD(0x118)  // row_shr:8
    DPPADD(0x142)  // row_bcast:15
    DPPADD(0x143)  // row_bcast:31 -> lane63 = wave sum
#undef DPPADD
    return v;
}

// One 128-thread block = one (b,k) group (R8/R10 config — measured optimum).
// use_ws==1: group partial streamed to dst=ws[g][1024]
// use_ws==0: fallback, global atomicAdd into dst=out (pre-zeroed)
__global__ __launch_bounds__(NTHR, 2) void sparse_wave(
    const float* __restrict__ x,
    const float* __restrict__ means,
    const float* __restrict__ sigmas,
    const float* __restrict__ values,
    const float* __restrict__ su,
    const float* __restrict__ ru,
    float* __restrict__ dst,
    int use_ws)
{
    const int tid = threadIdx.x;
    const int lane = tid & 63;
    const int w = tid >> 6;                         // wave within group (0/1)
    const int gk = blockIdx.x;                      // group id = b*KQ + k
    const int b = gk >> 7;                          // KQ == 128
    const float CEPS = (float)(1.0 - 1e-6);         // exact f32 of reference const

    __shared__ __align__(16) int htab[HSZ];         // group-shared hash (4 KB)
    __shared__ __align__(16) float acc[OUTN];       // group accumulator (4 KB)
    __shared__ float spart[WPG][CQ];                // per-wave partial S_c

    // ---- issue ALL independent global loads first (pure lane arithmetic
    // for addresses; overlaps LDS init + param loads + bpermutes) ----
    int cs[PPW], js[PPW];
    float2 uu[PPW];
    #pragma unroll
    for (int i = 0; i < PPW; ++i) {
        const int pt = w * 192 + i * 64 + lane;
        cs[i] = pt / 12; js[i] = pt % 12;
        if (js[i] >= 8)      uu[i] = *(const float2*)&ru[(gk * CQ + cs[i]) * 8 + (js[i] - 8) * 2];
        else if (js[i] >= 4) uu[i] = *(const float2*)&su[(gk * CQ + cs[i]) * 8 + (js[i] - 4) * 2];
        else                 uu[i] = make_float2(0.0f, 0.0f);
    }

    // lanes 0..31 of EACH wave hold gaussian cc==lane params in registers.
    // pi0/pi1 carry the exp2 prescale: exp(-0.5*sum((p-m)^2*inv^2))
    //   == exp2(-sum(((p-m)*inv*K2)^2)), K2 = sqrt(0.5*log2 e).
    float pm0 = 0.f, pm1 = 0.f, pi0 = 0.f, pi1 = 0.f, pv = 0.f;
    if (lane < CQ) {
        int cb = gk * CQ + lane;
        float2 mg = *(const float2*)&means[cb * 2];
        float2 sg = *(const float2*)&sigmas[cb * 2];
        pm0 = mg.x; pm1 = mg.y;
        pi0 = K2 * __fsqrt_rn(__fdiv_rn(1.0f, __fadd_rn(1e-6f, sg.x)));
        pi1 = K2 * __fsqrt_rn(__fdiv_rn(1.0f, __fadd_rn(1e-6f, sg.y)));
        pv  = values[cb];
    }

    // init (both waves cooperate)
    #pragma unroll
    for (int i = 0; i < HSZ / NTHR; ++i) htab[i * NTHR + tid] = -1;
    if (use_ws) {
        #pragma unroll
        for (int i = 0; i < OUTN / NTHR; ++i) acc[i * NTHR + tid] = 0.0f;
    }

    // ---- generate 3 points per lane ----
    int p0[PPW], p1[PPW];
    #pragma unroll
    for (int i = 0; i < PPW; ++i) {
        const int c = cs[i], j = js[i];
        const float mm0 = __shfl(pm0, c), mm1 = __shfl(pm1, c);  // ds_bpermute
        int q0, q1;
        if (j < 4) {
            // fm order: (T,T),(T,F),(F,T),(F,F); True->floor, False->ceil
            q0 = (int)((j >= 2) ? ceilf(mm0) : floorf(mm0));
            q1 = (int)((j & 1) ? ceilf(mm1) : floorf(mm1));
        } else if (j < 8) {
            // floor((u*(1-eps))*rng), pure f32 RN, no fma contraction
            q0 = (int)floorf(__fmul_rn(__fmul_rn(uu[i].x, CEPS), 1024.0f));
            q1 = (int)floorf(__fmul_rn(__fmul_rn(uu[i].y, CEPS), 1024.0f));
        } else {
            float mn0 = rintf(mm0), mn1 = rintf(mm1);  // jnp.round = half-even
            float lo0 = mn0 - 8.0f; if (lo0 < 0.0f) lo0 = 0.0f; if (mn0 + 8.0f > 1024.0f) lo0 = 1008.0f;
            float lo1 = mn1 - 8.0f; if (lo1 < 0.0f) lo1 = 0.0f; if (mn1 + 8.0f > 1024.0f) lo1 = 1008.0f;
            q0 = (int)floorf(__fadd_rn(__fmul_rn(__fmul_rn(uu[i].x, CEPS), 16.0f), lo0));
            q1 = (int)floorf(__fadd_rn(__fmul_rn(__fmul_rn(uu[i].y, CEPS), 16.0f), lo1));
        }
        p0[i] = q0; p1[i] = q1;
    }

    // prefetch x gathers (overlap with hash + density)
    float xv[PPW];
    #pragma unroll
    for (int i = 0; i < PPW; ++i) {
        int g1 = p1[i] < 0 ? 0 : (p1[i] > OUTN - 1 ? OUTN - 1 : p1[i]);  // jnp gather clamps
        xv[i] = x[b * OUTN + g1];
    }

    __syncthreads();  // htab/acc init visible to both waves before probing

    // ---- dedup via group-shared LDS hash; CAS insert is interleaving-safe:
    // exactly one thread per id wins, any survivor is numerically identical
    // to the reference's stable-sort pick ----
    unsigned dupm = 0u;
    #pragma unroll
    for (int i = 0; i < PPW; ++i) {
        const int myid = p0[i] * 1024 + p1[i];
        int slot = (int)(((unsigned)myid * 2654435761u) >> 22);
        while (true) {
            int prev = atomicCAS(&htab[slot], -1, myid);
            if (prev == -1) break;
            if (prev == myid) { dupm |= (1u << i); break; }
            slot = (slot + 1) & (HSZ - 1);
        }
    }

    const float pf0[PPW] = {(float)p0[0], (float)p0[1], (float)p0[2]};
    const float pf1[PPW] = {(float)p1[0], (float)p1[1], (float)p1[2]};

    // ---- densities for all 32 gaussians; keep e in registers; partial S_c ----
    float e[CQ][PPW];
    #pragma unroll
    for (int cc = 0; cc < CQ; ++cc) {
        const float m0 = __shfl(pm0, cc), m1 = __shfl(pm1, cc);  // v_readlane
        const float i0 = __shfl(pi0, cc), i1 = __shfl(pi1, cc);
        float s = 0.f;
        #pragma unroll
        for (int i = 0; i < PPW; ++i) {
            float d0 = (pf0[i] - m0) * i0;
            float d1 = (pf1[i] - m1) * i1;
            float t = exp2f(-(d0 * d0 + d1 * d1));   // neg folds into v_exp modifier
            t = ((dupm >> i) & 1u) ? 0.0f : t;
            e[cc][i] = t; s += t;
        }
        s = wave_red_dpp(s);
        if (lane == 63) spart[w][cc] = s;
    }
    __syncthreads();  // both waves' partial S_c in LDS

    // ---- combine S_c, form wn = value_c / S_c, accumulate vals ----
    float vals[PPW] = {0.f, 0.f, 0.f};
    #pragma unroll
    for (int cc = 0; cc < CQ; ++cc) {
        const float ss = spart[0][cc] + spart[1][cc];  // S_c > 0 (corners survive)
        const float wn = __shfl(pv, cc) / ss;
        #pragma unroll
        for (int i = 0; i < PPW; ++i) vals[i] += e[cc][i] * wn;
    }

    // ---- scatter ----
    #pragma unroll
    for (int i = 0; i < PPW; ++i) {
        if (!((dupm >> i) & 1u) && p0[i] >= 0 && p0[i] < OUTN) {  // jnp drops OOB
            float contrib = vals[i] * xv[i];
            if (use_ws) atomicAdd(&acc[p0[i]], contrib);          // LDS ds_add
            else        atomicAdd(&dst[b * OUTN + p0[i]], contrib);
        }
    }

    // ---- stream the group's 4KB partial out, coalesced float4 ----
    if (use_ws) {
        __syncthreads();  // all scatters into acc complete
        float* wsp = dst + (size_t)gk * OUTN;
        #pragma unroll
        for (int ii = 0; ii < OUTN / (NTHR * 4); ++ii) {
            int idx = ii * (NTHR * 4) + tid * 4;
            float4 v = *(const float4*)&acc[idx];
            *(float4*)&wsp[idx] = v;
        }
    }
}

// out[b][c] = sum over 128 k-partials; 8 threads per output element (16 each),
// LDS combine -> 64K threads for maximum latency-chain parallelism.
__global__ __launch_bounds__(256) void reduce_ws(const float* __restrict__ ws,
                                                 float* __restrict__ out) {
    const int t = blockIdx.x * blockDim.x + threadIdx.x;   // [0, 8*NACC)
    const int seg = t & 7;                                 // which 16-chunk of k
    const int oe = t >> 3;                                 // output element
    const int b = oe >> 10, cidx = oe & (OUTN - 1);
    const float* p = ws + (size_t)b * KQ * OUTN + (size_t)seg * 16 * OUTN + cidx;
    float s0 = 0.0f, s1 = 0.0f, s2 = 0.0f, s3 = 0.0f;
    #pragma unroll
    for (int k = 0; k < 16; k += 4) {
        s0 += p[(size_t)(k + 0) * OUTN];
        s1 += p[(size_t)(k + 1) * OUTN];
        s2 += p[(size_t)(k + 2) * OUTN];
        s3 += p[(size_t)(k + 3) * OUTN];
    }
    float s = (s0 + s1) + (s2 + s3);

    __shared__ float red[256];
    red[threadIdx.x] = s;
    __syncthreads();
    if (seg == 0) {
        float tot = ((red[threadIdx.x + 0] + red[threadIdx.x + 1]) +
                     (red[threadIdx.x + 2] + red[threadIdx.x + 3])) +
                    ((red[threadIdx.x + 4] + red[threadIdx.x + 5]) +
                     (red[threadIdx.x + 6] + red[threadIdx.x + 7]));
        out[oe] = tot;
    }
}

extern "C" void kernel_launch(void* const* d_in, const int* in_sizes, int n_in,
                              void* d_out, int out_size, void* d_ws, size_t ws_size,
                              hipStream_t stream) {
    const float* x      = (const float*)d_in[0];
    const float* means  = (const float*)d_in[1];
    const float* sigmas = (const float*)d_in[2];
    const float* values = (const float*)d_in[3];
    const float* su     = (const float*)d_in[4];
    const float* ru     = (const float*)d_in[5];
    float* out = (float*)d_out;
    float* ws  = (float*)d_ws;

    if (ws_size >= WS_NEED) {
        sparse_wave<<<dim3(NGROUP), dim3(NTHR), 0, stream>>>(
            x, means, sigmas, values, su, ru, ws, 1);
        reduce_ws<<<dim3(8 * NACC / 256), dim3(256), 0, stream>>>(ws, out);
    } else {
        zero_out<<<dim3((NACC + 255) / 256), dim3(256), 0, stream>>>(out);
        sparse_wave<<<dim3(NGROUP), dim3(NTHR), 0, stream>>>(
            x, means, sigmas, values, su, ru, out, 0);
    }
}

// Round 12
// 81.553 us; speedup vs baseline: 1.0143x; 1.0143x over previous
//
#include <hip/hip_runtime.h>

#define CQ 32
#define KQ 128
#define OUTN 1024
#define BQ 8
#define NACC (BQ * OUTN)
#define HSZ 1024
#define PPW 3                         // points per lane per wave (384 / 64 / 2)
#define WPG 2                         // waves per group
#define NTHR (WPG * 64)               // 128
#define NGROUP (BQ * KQ)              // 1024 groups = 1024 blocks
#define WS_NEED ((size_t)NGROUP * OUTN * sizeof(float))

__global__ void zero_out(float* __restrict__ out) {
    int i = blockIdx.x * blockDim.x + threadIdx.x;
    if (i < NACC) out[i] = 0.0f;
}

// wave64 sum via DPP; result valid in lane 63 (invalid-source lanes read 0).
__device__ __forceinline__ float wave_red_dpp(float v) {
#define DPPADD(ctrl)                                                              \
    {                                                                             \
        int t_ = __builtin_amdgcn_update_dpp(0, __float_as_int(v), (ctrl), 0xF,   \
                                             0xF, true);                          \
        v += __int_as_float(t_);                                                  \
    }
    DPPADD(0x111)  // row_shr:1
    DPPADD(0x112)  // row_shr:2
    DPPADD(0x114)  // row_shr:4
    DPPADD(0x118)  // row_shr:8
    DPPADD(0x142)  // row_bcast:15
    DPPADD(0x143)  // row_bcast:31 -> lane63 = wave sum
#undef DPPADD
    return v;
}

// One 128-thread block = one (b,k) group (R8/R10 config — measured optimum:
// WPG=2/PPW=3 beat both 1-wave/6-pt (R7) and 3-wave/2-pt (R9) variants).
// use_ws==1: group partial streamed to dst=ws[g][1024]
// use_ws==0: fallback, global atomicAdd into dst=out (pre-zeroed)
__global__ __launch_bounds__(NTHR, 2) void sparse_wave(
    const float* __restrict__ x,
    const float* __restrict__ means,
    const float* __restrict__ sigmas,
    const float* __restrict__ values,
    const float* __restrict__ su,
    const float* __restrict__ ru,
    float* __restrict__ dst,
    int use_ws)
{
    const int tid = threadIdx.x;
    const int lane = tid & 63;
    const int w = tid >> 6;                         // wave within group (0/1)
    const int gk = blockIdx.x;                      // group id = b*KQ + k
    const int b = gk >> 7;                          // KQ == 128
    const float CEPS = (float)(1.0 - 1e-6);         // exact f32 of reference const

    __shared__ __align__(16) int htab[HSZ];         // group-shared hash (4 KB)
    __shared__ __align__(16) float acc[OUTN];       // group accumulator (4 KB)
    __shared__ float spart[WPG][CQ];                // per-wave partial S_c

    // ---- issue ALL independent global loads first (pure lane arithmetic
    // for addresses; overlaps LDS init + param loads + bpermutes) ----
    int cs[PPW], js[PPW];
    float2 uu[PPW];
    #pragma unroll
    for (int i = 0; i < PPW; ++i) {
        const int pt = w * 192 + i * 64 + lane;
        cs[i] = pt / 12; js[i] = pt % 12;
        if (js[i] >= 8)      uu[i] = *(const float2*)&ru[(gk * CQ + cs[i]) * 8 + (js[i] - 8) * 2];
        else if (js[i] >= 4) uu[i] = *(const float2*)&su[(gk * CQ + cs[i]) * 8 + (js[i] - 4) * 2];
        else                 uu[i] = make_float2(0.0f, 0.0f);
    }

    // lanes 0..31 of EACH wave hold gaussian cc==lane params in registers
    float pm0 = 0.f, pm1 = 0.f, pi0 = 0.f, pi1 = 0.f, pv = 0.f;
    if (lane < CQ) {
        int cb = gk * CQ + lane;
        float2 mg = *(const float2*)&means[cb * 2];
        float2 sg = *(const float2*)&sigmas[cb * 2];
        pm0 = mg.x; pm1 = mg.y;
        pi0 = __fsqrt_rn(__fdiv_rn(1.0f, __fadd_rn(1e-6f, sg.x)));
        pi1 = __fsqrt_rn(__fdiv_rn(1.0f, __fadd_rn(1e-6f, sg.y)));
        pv  = values[cb];
    }

    // init (both waves cooperate)
    #pragma unroll
    for (int i = 0; i < HSZ / NTHR; ++i) htab[i * NTHR + tid] = -1;
    if (use_ws) {
        #pragma unroll
        for (int i = 0; i < OUTN / NTHR; ++i) acc[i * NTHR + tid] = 0.0f;
    }

    // ---- generate 3 points per lane ----
    int p0[PPW], p1[PPW];
    #pragma unroll
    for (int i = 0; i < PPW; ++i) {
        const int c = cs[i], j = js[i];
        const float mm0 = __shfl(pm0, c), mm1 = __shfl(pm1, c);  // ds_bpermute
        int q0, q1;
        if (j < 4) {
            // fm order: (T,T),(T,F),(F,T),(F,F); True->floor, False->ceil
            q0 = (int)((j >= 2) ? ceilf(mm0) : floorf(mm0));
            q1 = (int)((j & 1) ? ceilf(mm1) : floorf(mm1));
        } else if (j < 8) {
            // floor((u*(1-eps))*rng), pure f32 RN, no fma contraction
            q0 = (int)floorf(__fmul_rn(__fmul_rn(uu[i].x, CEPS), 1024.0f));
            q1 = (int)floorf(__fmul_rn(__fmul_rn(uu[i].y, CEPS), 1024.0f));
        } else {
            float mn0 = rintf(mm0), mn1 = rintf(mm1);  // jnp.round = half-even
            float lo0 = mn0 - 8.0f; if (lo0 < 0.0f) lo0 = 0.0f; if (mn0 + 8.0f > 1024.0f) lo0 = 1008.0f;
            float lo1 = mn1 - 8.0f; if (lo1 < 0.0f) lo1 = 0.0f; if (mn1 + 8.0f > 1024.0f) lo1 = 1008.0f;
            q0 = (int)floorf(__fadd_rn(__fmul_rn(__fmul_rn(uu[i].x, CEPS), 16.0f), lo0));
            q1 = (int)floorf(__fadd_rn(__fmul_rn(__fmul_rn(uu[i].y, CEPS), 16.0f), lo1));
        }
        p0[i] = q0; p1[i] = q1;
    }

    // prefetch x gathers (overlap with hash + density)
    float xv[PPW];
    #pragma unroll
    for (int i = 0; i < PPW; ++i) {
        int g1 = p1[i] < 0 ? 0 : (p1[i] > OUTN - 1 ? OUTN - 1 : p1[i]);  // jnp gather clamps
        xv[i] = x[b * OUTN + g1];
    }

    __syncthreads();  // htab/acc init visible to both waves before probing

    // ---- dedup via group-shared LDS hash; CAS insert is interleaving-safe:
    // exactly one thread per id wins, any survivor is numerically identical
    // to the reference's stable-sort pick ----
    unsigned dupm = 0u;
    #pragma unroll
    for (int i = 0; i < PPW; ++i) {
        const int myid = p0[i] * 1024 + p1[i];
        int slot = (int)(((unsigned)myid * 2654435761u) >> 22);
        while (true) {
            int prev = atomicCAS(&htab[slot], -1, myid);
            if (prev == -1) break;
            if (prev == myid) { dupm |= (1u << i); break; }
            slot = (slot + 1) & (HSZ - 1);
        }
    }

    const float pf0[PPW] = {(float)p0[0], (float)p0[1], (float)p0[2]};
    const float pf1[PPW] = {(float)p1[0], (float)p1[1], (float)p1[2]};

    // ---- densities for all 32 gaussians; keep e in registers; partial S_c ----
    float e[CQ][PPW];
    #pragma unroll
    for (int cc = 0; cc < CQ; ++cc) {
        const float m0 = __shfl(pm0, cc), m1 = __shfl(pm1, cc);  // v_readlane
        const float i0 = __shfl(pi0, cc), i1 = __shfl(pi1, cc);
        float s = 0.f;
        #pragma unroll
        for (int i = 0; i < PPW; ++i) {
            float d0 = (pf0[i] - m0) * i0;
            float d1 = (pf1[i] - m1) * i1;
            float t = __expf(-0.5f * (d0 * d0 + d1 * d1));
            t = ((dupm >> i) & 1u) ? 0.0f : t;
            e[cc][i] = t; s += t;
        }
        s = wave_red_dpp(s);
        if (lane == 63) spart[w][cc] = s;
    }
    __syncthreads();  // both waves' partial S_c in LDS

    // ---- combine S_c, form wn = value_c / S_c, accumulate vals ----
    float vals[PPW] = {0.f, 0.f, 0.f};
    #pragma unroll
    for (int cc = 0; cc < CQ; ++cc) {
        const float ss = spart[0][cc] + spart[1][cc];  // S_c > 0 (corners survive)
        const float wn = __shfl(pv, cc) / ss;
        #pragma unroll
        for (int i = 0; i < PPW; ++i) vals[i] += e[cc][i] * wn;
    }

    // ---- scatter ----
    #pragma unroll
    for (int i = 0; i < PPW; ++i) {
        if (!((dupm >> i) & 1u) && p0[i] >= 0 && p0[i] < OUTN) {  // jnp drops OOB
            float contrib = vals[i] * xv[i];
            if (use_ws) atomicAdd(&acc[p0[i]], contrib);          // LDS ds_add
            else        atomicAdd(&dst[b * OUTN + p0[i]], contrib);
        }
    }

    // ---- stream the group's 4KB partial out, coalesced float4 ----
    if (use_ws) {
        __syncthreads();  // all scatters into acc complete
        float* wsp = dst + (size_t)gk * OUTN;
        #pragma unroll
        for (int ii = 0; ii < OUTN / (NTHR * 4); ++ii) {
            int idx = ii * (NTHR * 4) + tid * 4;
            float4 v = *(const float4*)&acc[idx];
            *(float4*)&wsp[idx] = v;
        }
    }
}

// out[b][c] = sum over 128 k-partials; 4 threads per output element (32 each),
// LDS combine -> 32K threads (R10 config — measured best).
__global__ __launch_bounds__(256) void reduce_ws(const float* __restrict__ ws,
                                                 float* __restrict__ out) {
    const int t = blockIdx.x * blockDim.x + threadIdx.x;   // [0, 4*NACC)
    const int seg = t & 3;                                 // which 32-chunk of k
    const int oe = t >> 2;                                 // output element
    const int b = oe >> 10, cidx = oe & (OUTN - 1);
    const float* p = ws + (size_t)b * KQ * OUTN + (size_t)seg * 32 * OUTN + cidx;
    float s0 = 0.0f, s1 = 0.0f, s2 = 0.0f, s3 = 0.0f;
    #pragma unroll
    for (int k = 0; k < 32; k += 4) {
        s0 += p[(size_t)(k + 0) * OUTN];
        s1 += p[(size_t)(k + 1) * OUTN];
        s2 += p[(size_t)(k + 2) * OUTN];
        s3 += p[(size_t)(k + 3) * OUTN];
    }
    float s = (s0 + s1) + (s2 + s3);

    __shared__ float red[256];
    red[threadIdx.x] = s;
    __syncthreads();
    if (seg == 0) {
        float tot = red[threadIdx.x] + red[threadIdx.x + 1] +
                    red[threadIdx.x + 2] + red[threadIdx.x + 3];
        out[oe] = tot;
    }
}

extern "C" void kernel_launch(void* const* d_in, const int* in_sizes, int n_in,
                              void* d_out, int out_size, void* d_ws, size_t ws_size,
                              hipStream_t stream) {
    const float* x      = (const float*)d_in[0];
    const float* means  = (const float*)d_in[1];
    const float* sigmas = (const float*)d_in[2];
    const float* values = (const float*)d_in[3];
    const float* su     = (const float*)d_in[4];
    const float* ru     = (const float*)d_in[5];
    float* out = (float*)d_out;
    float* ws  = (float*)d_ws;

    if (ws_size >= WS_NEED) {
        sparse_wave<<<dim3(NGROUP), dim3(NTHR), 0, stream>>>(
            x, means, sigmas, values, su, ru, ws, 1);
        reduce_ws<<<dim3(4 * NACC / 256), dim3(256), 0, stream>>>(ws, out);
    } else {
        zero_out<<<dim3((NACC + 255) / 256), dim3(256), 0, stream>>>(out);
        sparse_wave<<<dim3(NGROUP), dim3(NTHR), 0, stream>>>(
            x, means, sigmas, values, su, ru, out, 0);
    }
}